// Round 11
// baseline (209.099 us; speedup 1.0000x reference)
//
#include <hip/hip_runtime.h>
#include <hip/hip_bf16.h>
#include <stdint.h>

typedef __attribute__((ext_vector_type(8))) __bf16 bf16x8;
typedef __attribute__((ext_vector_type(4))) __bf16 bf16x4;
typedef __attribute__((ext_vector_type(4))) float f32x4;

#define AS1 __attribute__((address_space(1)))
#define AS3 __attribute__((address_space(3)))

__device__ __forceinline__ void load_lds16(const void* g, void* l) {
    __builtin_amdgcn_global_load_lds((const AS1 void*)g, (AS3 void*)l, 16, 0, 0);
}

__device__ __forceinline__ float m3(float a, float b, float c) {
    return fmaxf(fmaxf(a, b), c);  // clang fuses to v_max3_f32
}

constexpr float QSCALE = 0.18033688011112042f;  // 64^-0.5 * log2(e)

// sigma: storage position of kv (0..31) within a 32-column block of Vt,
// chosen so the PV B-operand slots match the P-register slots (phi mapping).
__device__ __forceinline__ int sigma32(int kv) {
    return (kv < 16) ? ((kv >> 2) * 8 + (kv & 3))
                     : (((kv - 16) >> 2) * 8 + 4 + ((kv - 16) & 3));
}

// ---------------------------------------------------------------------------
// fused preamble: job 0 = x fp32->bf16; job 1 = transpose+cvt w_qkv;
// job 2 = transpose+cvt w_proj. One launch instead of three.
__device__ __forceinline__ void tconv_body(const float* __restrict__ src,
                                           __bf16* __restrict__ dst,
                                           int R, int C, int c0, int r0, int t) {
    __shared__ float tile[32][33];
    const int tx = t & 31, ty = t >> 5;  // 32 x 8
    #pragma unroll
    for (int i = 0; i < 32; i += 8)
        tile[ty + i][tx] = src[(size_t)(r0 + ty + i) * C + c0 + tx];
    __syncthreads();
    #pragma unroll
    for (int i = 0; i < 32; i += 8)
        dst[(size_t)(c0 + ty + i) * R + r0 + tx] = (__bf16)tile[tx][ty + i];
}

__global__ __launch_bounds__(256)
void prep(const float* __restrict__ x, const float* __restrict__ w_qkv,
          const float* __restrict__ w_proj, __bf16* __restrict__ x_bf,
          __bf16* __restrict__ wqkvT, __bf16* __restrict__ wprojT) {
    const int bid = blockIdx.x;
    const int t = threadIdx.x;
    if (bid < 1024) {
        const float4* xv = (const float4*)x;
        bf16x4* ov = (bf16x4*)x_bf;
        int i = bid * 256 + t;
        #pragma unroll
        for (int it = 0; it < 4; ++it, i += 262144) {
            float4 v = xv[i];
            bf16x4 r;
            r[0] = (__bf16)v.x; r[1] = (__bf16)v.y;
            r[2] = (__bf16)v.z; r[3] = (__bf16)v.w;
            ov[i] = r;
        }
    } else if (bid < 1024 + 3072) {
        const int b = bid - 1024;             // w_qkv: 96 x 32 tiles
        tconv_body(w_qkv, wqkvT, 1024, 3072, (b % 96) * 32, (b / 96) * 32, t);
    } else {
        const int b = bid - 4096;             // w_proj: 32 x 32 tiles
        tconv_body(w_proj, wprojT, 1024, 1024, (b & 31) * 32, (b >> 5) * 32, t);
    }
}

// ---------------------------------------------------------------------------
// 128x128 bf16 GEMM, Bt is [N][K]. C = A @ Bt^T + bias. (r10 version)
template <int MODE>
__global__ __launch_bounds__(256)
void gemm128(const __bf16* __restrict__ A, const __bf16* __restrict__ Bt,
             const float* __restrict__ bias, void* __restrict__ outp,
             int M, int Nn, int K) {
    __shared__ __bf16 As[3][128][32];
    __shared__ __bf16 Bs[3][128][32];
    const int t = threadIdx.x;
    const int w = t >> 6, l = t & 63;
    const int lrow = l & 15, lhi = l >> 4;
    const int wr = (w >> 1) * 64, wc = (w & 1) * 64;

    int m0, n0;
    {
        const int f = blockIdx.x + blockIdx.y * gridDim.x;
        if ((gridDim.y & 3) == 0 && (gridDim.x & 1) == 0) {
            const int c = f & 7, i = f >> 3;
            const int nch = gridDim.x >> 1;
            const int mrow = i / nch, ncol = i % nch;
            m0 = ((c & 3) * (gridDim.y >> 2) + mrow) * 128;
            n0 = ((c >> 2) * nch + ncol) * 128;
        } else {
            m0 = blockIdx.y * 128; n0 = blockIdx.x * 128;
        }
    }

    f32x4 acc[4][4] = {};

    const int sr = t >> 2;
    const int dc = (t & 3) * 8;
    const int scsw = ((t & 3) ^ ((sr >> 1) & 3)) * 8;
    const __bf16* agb = A + (size_t)(m0 + sr) * K + scsw;
    const __bf16* bgb = Bt + (size_t)(n0 + sr) * K + scsw;

#define STAGE_G(BUF, KT)                                                   \
    { load_lds16(agb + (KT), &As[BUF][sr][dc]);                            \
      load_lds16(agb + (size_t)64 * K + (KT), &As[BUF][64 + sr][dc]);      \
      load_lds16(bgb + (KT), &Bs[BUF][sr][dc]);                            \
      load_lds16(bgb + (size_t)64 * K + (KT), &Bs[BUF][64 + sr][dc]); }

    STAGE_G(0, 0)
    STAGE_G(1, 32)

    const int rofs = (lhi ^ ((lrow >> 1) & 3)) << 4;
    const int nt = K >> 5;
    int cur = 0, pre = 2;
    for (int tt = 0; tt < nt; ++tt) {
        if (tt + 2 < nt) {
            STAGE_G(pre, (tt + 2) * 32)
            asm volatile("s_waitcnt vmcnt(8)" ::: "memory");
        } else if (tt + 1 < nt) {
            asm volatile("s_waitcnt vmcnt(4)" ::: "memory");
        } else {
            asm volatile("s_waitcnt vmcnt(0)" ::: "memory");
        }
        __builtin_amdgcn_sched_barrier(0);
        __builtin_amdgcn_s_barrier();
        __builtin_amdgcn_sched_barrier(0);

        bf16x8 af[4], bfv[4];
        #pragma unroll
        for (int i = 0; i < 4; ++i)
            af[i] = *(const bf16x8*)((const char*)&As[cur][wr + i * 16 + lrow][0] + rofs);
        #pragma unroll
        for (int j = 0; j < 4; ++j)
            bfv[j] = *(const bf16x8*)((const char*)&Bs[cur][wc + j * 16 + lrow][0] + rofs);
        __builtin_amdgcn_s_setprio(1);
        #pragma unroll
        for (int i = 0; i < 4; ++i)
            #pragma unroll
            for (int j = 0; j < 4; ++j)
                acc[i][j] = __builtin_amdgcn_mfma_f32_16x16x32_bf16(
                    af[i], bfv[j], acc[i][j], 0, 0, 0);
        __builtin_amdgcn_s_setprio(0);

        __builtin_amdgcn_sched_barrier(0);
        asm volatile("s_waitcnt lgkmcnt(0)" ::: "memory");
        __builtin_amdgcn_s_barrier();
        __builtin_amdgcn_sched_barrier(0);

        cur = (cur == 2) ? 0 : cur + 1;
        pre = (pre == 2) ? 0 : pre + 1;
    }
#undef STAGE_G

    #pragma unroll
    for (int i = 0; i < 4; ++i)
        #pragma unroll
        for (int j = 0; j < 4; ++j)
            #pragma unroll
            for (int r = 0; r < 4; ++r) {
                int row = m0 + wr + i * 16 + lhi * 4 + r;
                int col = n0 + wc + j * 16 + lrow;
                float val = acc[i][j][r] + bias[col];
                if (MODE == 0) {
                    int which = col >> 10;          // 0=q 1=k 2=v
                    int h = (col >> 6) & 15;
                    int d = col & 63;
                    int b = row >> 11;
                    int n = row & 2047;
                    int bh = (b << 4) + h;
                    if (which == 2) {
                        ((__bf16*)outp)[(size_t)2 * (32 * 2048 * 64) +
                                        ((size_t)bh * 64 + d) * 2048 +
                                        (n & ~31) + sigma32(n & 31)] = (__bf16)val;
                    } else {
                        if (which == 0) val *= QSCALE;
                        ((__bf16*)outp)[(size_t)which * (32 * 2048 * 64) +
                                        ((size_t)bh * 2048 + n) * 64 + d] = (__bf16)val;
                    }
                } else {
                    ((float*)outp)[(size_t)row * Nn + col] = val;
                }
            }
}

// ---------------------------------------------------------------------------
// flash attention, swapped-QK^T, in-register P, swizzled K/V LDS, KVBLK=64,
// TRIPLE-buffered LDS + att[2] software pipeline (T15): step t issues QK(t)
// into one S-register set while finishing softmax+PV of tile t-1 from the
// other set -> QK MFMA (matrix pipe) overlaps softmax VALU of prev tile.
// Each wave owns 32 q-rows (2 groups of 16 sharing K/V fragments).
// q,k: [32][2048][64] (q pre-scaled)   vt: [32][64][2048] sigma-interleaved
// out: [4096][1024] bf16
__global__ __launch_bounds__(256)
void attn_fwd(const __bf16* __restrict__ q, const __bf16* __restrict__ k,
              const __bf16* __restrict__ vt, __bf16* __restrict__ out) {
    __shared__ __bf16 KsV[3][64][64];
    __shared__ __bf16 VsV[3][64][64];
    char* ksB = (char*)KsV;
    char* vsB = (char*)VsV;

    const int t = threadIdx.x;
    const int w = t >> 6, l = t & 63;
    const int lrow = l & 15, lhi = l >> 4;
    const int bh = blockIdx.y;
    const int q0 = blockIdx.x * 128 + w * 32;

    const __bf16* qp = q + ((size_t)bh * 2048 + q0) * 64;
    bf16x8 qfA0 = *(const bf16x8*)(qp + lrow * 64 + lhi * 8);
    bf16x8 qfA1 = *(const bf16x8*)(qp + lrow * 64 + 32 + lhi * 8);
    bf16x8 qfB0 = *(const bf16x8*)(qp + (16 + lrow) * 64 + lhi * 8);
    bf16x8 qfB1 = *(const bf16x8*)(qp + (16 + lrow) * 64 + 32 + lhi * 8);

    f32x4 oA[4] = {}, oB[4] = {};
    float mA = -1e30f, mB = -1e30f;
    float lA = 0.f, lB = 0.f;

    const __bf16* kg = k + (size_t)bh * 2048 * 64;
    const __bf16* vg = vt + (size_t)bh * 64 * 2048;

    const int sr = t >> 3;
    const int sw8 = ((t & 7) ^ (sr & 7)) * 8;
    const int rsw = (lrow & 7) << 4;
    const int t16 = t * 16;

    // prologue: stage tile 0 into buf 0
    {
        char* kd = ksB + t16;
        char* vd = vsB + t16;
        load_lds16(kg + (size_t)sr * 64 + sw8, kd);
        load_lds16(kg + (size_t)(32 + sr) * 64 + sw8, kd + 4096);
        load_lds16(vg + (size_t)sr * 2048 + sw8, vd);
        load_lds16(vg + (size_t)(32 + sr) * 2048 + sw8, vd + 4096);
    }

    // staging pointers advance tile-sequentially (tiles 1,2,...,31)
    const __bf16* kst  = kg + (size_t)(64 + sr) * 64 + sw8;
    const __bf16* kst2 = kst + 32 * 64;
    const __bf16* vst  = vg + (size_t)sr * 2048 + 64 + sw8;
    const __bf16* vst2 = vst + 32 * 2048;

    const int o0 = (lhi << 4) ^ rsw;
    const int o4 = ((4 + lhi) << 4) ^ rsw;

#define STAGE(DB)                                                              \
    { char* kd = ksB + (DB) * 8192 + t16;                                      \
      char* vd = vsB + (DB) * 8192 + t16;                                      \
      load_lds16(kst, kd);  load_lds16(kst2, kd + 4096);                       \
      load_lds16(vst, vd);  load_lds16(vst2, vd + 4096);                       \
      kst += 4096; kst2 += 4096; vst += 64; vst2 += 64; }

#define QK_TILE(SA0, SA1, SA2, SA3, SB0, SB1, SB2, SB3, KBUF)                  \
    { const char* kb = ksB + (KBUF) * 8192 + lrow * 128;                       \
      SA0 = (f32x4){}; SA1 = (f32x4){}; SA2 = (f32x4){}; SA3 = (f32x4){};      \
      SB0 = (f32x4){}; SB1 = (f32x4){}; SB2 = (f32x4){}; SB3 = (f32x4){};      \
      bf16x8 kf0, kf1;                                                         \
      __builtin_amdgcn_s_setprio(1);                                           \
      kf0 = *(const bf16x8*)(kb + o0);                                         \
      kf1 = *(const bf16x8*)(kb + o4);                                         \
      SA0 = __builtin_amdgcn_mfma_f32_16x16x32_bf16(kf0, qfA0, SA0, 0, 0, 0);  \
      SA0 = __builtin_amdgcn_mfma_f32_16x16x32_bf16(kf1, qfA1, SA0, 0, 0, 0);  \
      SB0 = __builtin_amdgcn_mfma_f32_16x16x32_bf16(kf0, qfB0, SB0, 0, 0, 0);  \
      SB0 = __builtin_amdgcn_mfma_f32_16x16x32_bf16(kf1, qfB1, SB0, 0, 0, 0);  \
      kf0 = *(const bf16x8*)(kb + 2048 + o0);                                  \
      kf1 = *(const bf16x8*)(kb + 2048 + o4);                                  \
      SA1 = __builtin_amdgcn_mfma_f32_16x16x32_bf16(kf0, qfA0, SA1, 0, 0, 0);  \
      SA1 = __builtin_amdgcn_mfma_f32_16x16x32_bf16(kf1, qfA1, SA1, 0, 0, 0);  \
      SB1 = __builtin_amdgcn_mfma_f32_16x16x32_bf16(kf0, qfB0, SB1, 0, 0, 0);  \
      SB1 = __builtin_amdgcn_mfma_f32_16x16x32_bf16(kf1, qfB1, SB1, 0, 0, 0);  \
      kf0 = *(const bf16x8*)(kb + 4096 + o0);                                  \
      kf1 = *(const bf16x8*)(kb + 4096 + o4);                                  \
      SA2 = __builtin_amdgcn_mfma_f32_16x16x32_bf16(kf0, qfA0, SA2, 0, 0, 0);  \
      SA2 = __builtin_amdgcn_mfma_f32_16x16x32_bf16(kf1, qfA1, SA2, 0, 0, 0);  \
      SB2 = __builtin_amdgcn_mfma_f32_16x16x32_bf16(kf0, qfB0, SB2, 0, 0, 0);  \
      SB2 = __builtin_amdgcn_mfma_f32_16x16x32_bf16(kf1, qfB1, SB2, 0, 0, 0);  \
      kf0 = *(const bf16x8*)(kb + 6144 + o0);                                  \
      kf1 = *(const bf16x8*)(kb + 6144 + o4);                                  \
      SA3 = __builtin_amdgcn_mfma_f32_16x16x32_bf16(kf0, qfA0, SA3, 0, 0, 0);  \
      SA3 = __builtin_amdgcn_mfma_f32_16x16x32_bf16(kf1, qfA1, SA3, 0, 0, 0);  \
      SB3 = __builtin_amdgcn_mfma_f32_16x16x32_bf16(kf0, qfB0, SB3, 0, 0, 0);  \
      SB3 = __builtin_amdgcn_mfma_f32_16x16x32_bf16(kf1, qfB1, SB3, 0, 0, 0);  \
      __builtin_amdgcn_s_setprio(0); }

#define SM_PV(SA0, SA1, SA2, SA3, SB0, SB1, SB2, SB3, VBUF)                    \
    { const char* vb = vsB + (VBUF) * 8192 + lrow * 128;                       \
      float u0 = m3(SA0[0], SA0[1], SA0[2]);                                   \
      float u1 = m3(SA0[3], SA1[0], SA1[1]);                                   \
      float u2 = m3(SA1[2], SA1[3], SA2[0]);                                   \
      float u3 = m3(SA2[1], SA2[2], SA2[3]);                                   \
      float u4 = m3(SA3[0], SA3[1], SA3[2]);                                   \
      float tmA = fmaxf(m3(u0, u1, u2), m3(u3, u4, SA3[3]));                   \
      float v0 = m3(SB0[0], SB0[1], SB0[2]);                                   \
      float v1 = m3(SB0[3], SB1[0], SB1[1]);                                   \
      float v2 = m3(SB1[2], SB1[3], SB2[0]);                                   \
      float v3 = m3(SB2[1], SB2[2], SB2[3]);                                   \
      float v4 = m3(SB3[0], SB3[1], SB3[2]);                                   \
      float tmB = fmaxf(m3(v0, v1, v2), m3(v3, v4, SB3[3]));                   \
      tmA = fmaxf(tmA, __shfl_xor(tmA, 16, 64));                               \
      tmA = fmaxf(tmA, __shfl_xor(tmA, 32, 64));                               \
      tmB = fmaxf(tmB, __shfl_xor(tmB, 16, 64));                               \
      tmB = fmaxf(tmB, __shfl_xor(tmB, 32, 64));                               \
      if (!__all(tmA <= mA + 8.0f && tmB <= mB + 8.0f)) {                      \
          float mnA = fmaxf(mA, tmA), mnB = fmaxf(mB, tmB);                    \
          float cA = __builtin_amdgcn_exp2f(mA - mnA);                         \
          float cB = __builtin_amdgcn_exp2f(mB - mnB);                         \
          lA *= cA; lB *= cB;                                                  \
          _Pragma("unroll")                                                    \
          for (int dt = 0; dt < 4; ++dt)                                       \
              _Pragma("unroll")                                                \
              for (int r = 0; r < 4; ++r) { oA[dt][r] *= cA; oB[dt][r] *= cB; }\
          mA = mnA; mB = mnB;                                                  \
      }                                                                        \
      float pA[16], pB[16];                                                    \
      _Pragma("unroll")                                                        \
      for (int r = 0; r < 4; ++r) {                                            \
          pA[r]      = __builtin_amdgcn_exp2f(SA0[r] - mA);                    \
          pA[4 + r]  = __builtin_amdgcn_exp2f(SA1[r] - mA);                    \
          pA[8 + r]  = __builtin_amdgcn_exp2f(SA2[r] - mA);                    \
          pA[12 + r] = __builtin_amdgcn_exp2f(SA3[r] - mA);                    \
          pB[r]      = __builtin_amdgcn_exp2f(SB0[r] - mB);                    \
          pB[4 + r]  = __builtin_amdgcn_exp2f(SB1[r] - mB);                    \
          pB[8 + r]  = __builtin_amdgcn_exp2f(SB2[r] - mB);                    \
          pB[12 + r] = __builtin_amdgcn_exp2f(SB3[r] - mB);                    \
      }                                                                        \
      float rsA = 0.f, rsB = 0.f;                                              \
      _Pragma("unroll")                                                        \
      for (int j = 0; j < 16; ++j) { rsA += pA[j]; rsB += pB[j]; }             \
      lA += rsA; lB += rsB;                                                    \
      bf16x8 pfA0, pfA1, pfB0, pfB1;                                           \
      _Pragma("unroll")                                                        \
      for (int j = 0; j < 8; ++j) {                                            \
          pfA0[j] = (__bf16)pA[j]; pfA1[j] = (__bf16)pA[8 + j];                \
          pfB0[j] = (__bf16)pB[j]; pfB1[j] = (__bf16)pB[8 + j];                \
      }                                                                        \
      __builtin_amdgcn_s_setprio(1);                                           \
      _Pragma("unroll")                                                        \
      for (int dt = 0; dt < 4; ++dt) {                                         \
          bf16x8 vf0 = *(const bf16x8*)(vb + dt * 2048 + o0);                  \
          bf16x8 vf1 = *(const bf16x8*)(vb + dt * 2048 + o4);                  \
          oA[dt] = __builtin_amdgcn_mfma_f32_16x16x32_bf16(vf0, pfA0, oA[dt], 0, 0, 0); \
          oA[dt] = __builtin_amdgcn_mfma_f32_16x16x32_bf16(vf1, pfA1, oA[dt], 0, 0, 0); \
          oB[dt] = __builtin_amdgcn_mfma_f32_16x16x32_bf16(vf0, pfB0, oB[dt], 0, 0, 0); \
          oB[dt] = __builtin_amdgcn_mfma_f32_16x16x32_bf16(vf1, pfB1, oB[dt], 0, 0, 0); \
      }                                                                        \
      __builtin_amdgcn_s_setprio(0); }

    // two S-register sets (X = even tiles, Y = odd tiles), statically named
    f32x4 xA0, xA1, xA2, xA3, xB0, xB1, xB2, xB3;
    f32x4 yA0, yA1, yA2, yA3, yB0, yB1, yB2, yB3;

    // step 0: QK(0) only
    __syncthreads();
    STAGE(1)
    QK_TILE(xA0, xA1, xA2, xA3, xB0, xB1, xB2, xB3, 0)

    for (int tt = 1; tt < 31; tt += 2) {
        const int a = tt % 3;
        const int b = (tt + 1) % 3;
        const int c = (tt + 2) % 3;   // == (tt-1)%3
        // step tt (odd): QK(tt)->Y from buf a; finish tile tt-1 (X), V buf c
        __syncthreads();
        STAGE(b)
        QK_TILE(yA0, yA1, yA2, yA3, yB0, yB1, yB2, yB3, a)
        SM_PV(xA0, xA1, xA2, xA3, xB0, xB1, xB2, xB3, c)
        // step tt+1 (even): QK(tt+1)->X from buf b; finish tile tt (Y), V buf a
        __syncthreads();
        STAGE(c)
        QK_TILE(xA0, xA1, xA2, xA3, xB0, xB1, xB2, xB3, b)
        SM_PV(yA0, yA1, yA2, yA3, yB0, yB1, yB2, yB3, a)
    }
    // step 31: QK(31)->Y from buf 1; finish tile 30 (X), V buf 0
    __syncthreads();
    QK_TILE(yA0, yA1, yA2, yA3, yB0, yB1, yB2, yB3, 1)
    SM_PV(xA0, xA1, xA2, xA3, xB0, xB1, xB2, xB3, 0)
    // drain: finish tile 31 (Y), V buf 1
    SM_PV(yA0, yA1, yA2, yA3, yB0, yB1, yB2, yB3, 1)

#undef STAGE
#undef QK_TILE
#undef SM_PV

    lA += __shfl_xor(lA, 16, 64); lA += __shfl_xor(lA, 32, 64);
    lB += __shfl_xor(lB, 16, 64); lB += __shfl_xor(lB, 32, 64);
    float invA = __builtin_amdgcn_rcpf(lA);
    float invB = __builtin_amdgcn_rcpf(lB);

    const int b = bh >> 4, h = bh & 15;
    __bf16* orowA = out + ((size_t)(b * 2048 + q0 + lrow)) * 1024 + h * 64;
    __bf16* orowB = out + ((size_t)(b * 2048 + q0 + 16 + lrow)) * 1024 + h * 64;
    #pragma unroll
    for (int dt = 0; dt < 4; ++dt) {
        bf16x4 ovA, ovB;
        #pragma unroll
        for (int r = 0; r < 4; ++r) {
            ovA[r] = (__bf16)(oA[dt][r] * invA);
            ovB[r] = (__bf16)(oB[dt][r] * invB);
        }
        *(bf16x4*)(orowA + dt * 16 + lhi * 4) = ovA;
        *(bf16x4*)(orowB + dt * 16 + lhi * 4) = ovB;
    }
}

// ---------------------------------------------------------------------------
extern "C" void kernel_launch(void* const* d_in, const int* in_sizes, int n_in,
                              void* d_out, int out_size, void* d_ws, size_t ws_size,
                              hipStream_t stream) {
    const float* x      = (const float*)d_in[0];
    const float* w_qkv  = (const float*)d_in[1];
    const float* b_qkv  = (const float*)d_in[2];
    const float* w_proj = (const float*)d_in[3];
    const float* b_proj = (const float*)d_in[4];
    float* out = (float*)d_out;

    __bf16* ws     = (__bf16*)d_ws;
    __bf16* x_bf   = ws;                          // 4096*1024
    __bf16* wqkvT  = x_bf + 4096 * 1024;          // 3072*1024
    __bf16* wprojT = wqkvT + 3072 * 1024;         // 1024*1024
    __bf16* qb     = wprojT + 1024 * 1024;        // 32*2048*64
    __bf16* kb     = qb + 32 * 2048 * 64;
    __bf16* vtb    = kb + 32 * 2048 * 64;         // sigma-interleaved V^T
    __bf16* attn   = vtb + 32 * 2048 * 64;        // 4096*1024

    prep<<<5120, 256, 0, stream>>>(x, w_qkv, w_proj, x_bf, wqkvT, wprojT);
    gemm128<0><<<dim3(24, 32), 256, 0, stream>>>(x_bf, wqkvT, b_qkv, qb, 4096, 3072, 1024);
    attn_fwd<<<dim3(16, 32), 256, 0, stream>>>(qb, kb, vtb, attn);
    gemm128<1><<<dim3(8, 32), 256, 0, stream>>>(attn, wprojT, b_proj, out, 4096, 1024, 1024);
}